// Round 8
// baseline (222.214 us; speedup 1.0000x reference)
//
#include <hip/hip_runtime.h>

#define DH 128
#define DW 128
#define DB 8
#define DC 64
constexpr int HW = DH * DW;

typedef __attribute__((ext_vector_type(4))) float f32x4;
typedef __attribute__((ext_vector_type(16))) float f32x16;
typedef __attribute__((ext_vector_type(8))) short bf16x8;
typedef __attribute__((ext_vector_type(4))) unsigned int u32x4;

__device__ __forceinline__ unsigned short f2b(float f) {
    unsigned int u = __builtin_bit_cast(unsigned int, f);
    u = (u + 0x7FFFu + ((u >> 16) & 1u)) >> 16;   // RNE
    return (unsigned short)u;
}
__device__ __forceinline__ float b2f(unsigned short h) {
    unsigned int u = ((unsigned int)h) << 16;
    return __builtin_bit_cast(float, u);
}

// ---------- prep: NCHW fp32 -> HWC bf16 transpose + weight repack ----------
__global__ __launch_bounds__(256) void prep_kernel(
    const float* __restrict__ x, const float* __restrict__ wo,
    const float* __restrict__ wc, unsigned short* __restrict__ xh,
    unsigned short* __restrict__ wt1, unsigned short* __restrict__ wt2)
{
    __shared__ unsigned short smx[64 * 80];
    const int blk = blockIdx.x;
    const int t = threadIdx.x;
    if (blk < 2048) {
        const int b = blk >> 8;
        const int p0 = (blk & 255) * 64;
        const int ci = t >> 2, q = t & 3;
        const float* xr = x + ((size_t)b * 64 + ci) * HW + p0;
#pragma unroll
        for (int j = 0; j < 4; ++j) {
            int pix = (j * 4 + q) * 4;
            float4 v = *(const float4*)(xr + pix);
            smx[(pix + 0) * 80 + ci] = f2b(v.x);
            smx[(pix + 1) * 80 + ci] = f2b(v.y);
            smx[(pix + 2) * 80 + ci] = f2b(v.z);
            smx[(pix + 3) * 80 + ci] = f2b(v.w);
        }
        __syncthreads();
        unsigned short* outp = xh + ((size_t)b * HW + p0) * 64;
        for (int i = t; i < 512; i += 256) {
            int pix = i >> 3, cq = i & 7;
            u32x4 v = *(const u32x4*)(smx + pix * 80 + cq * 8);
            *(u32x4*)(outp + pix * 64 + cq * 8) = v;
        }
    } else {
        int id = (blk - 2048) * 256 + t;
        const int N1 = 9 * 128 * 64, N2 = 9 * 64 * 64;
        if (id < N1) {
            int tp = id / (128 * 64);
            int rem = id - tp * 128 * 64;
            int co = rem >> 6, ci = rem & 63;
            wt1[id] = f2b(wo[(co * 64 + ci) * 9 + tp]);
        } else if (id < N1 + N2) {
            int k = id - N1;
            int tp = k / (64 * 64);
            int rem = k - tp * 64 * 64;
            int co = rem >> 6, ci = rem & 63;
            wt2[k] = f2b(wc[(co * 64 + ci) * 9 + tp]);
        }
    }
}

// ---------- conv1: 3x3 implicit GEMM, barrier-free K-loop ----------
// 512 thr = 8 waves. Tile 16x16 px x 128 co. Halo [324hp][64ci] bf16 in LDS
// (swz ^(hp&7)<<4). A-fragments read directly from global wt (L2-hot,
// coalesced 16B/lane). ONE barrier total. Output: CHW bf16 (offsets layout).
__global__ __launch_bounds__(512, 4) void conv1_kernel(
    const unsigned short* __restrict__ xh,   // bf16 HWC [b][p][64]
    const unsigned short* __restrict__ wt,   // bf16 [9][128][64]
    unsigned short* __restrict__ outp)       // bf16 CHW [b][128][HW]
{
    __shared__ char sm[41472];
    const int tid = threadIdx.x;
    const int b = blockIdx.y;
    const int ty0 = (blockIdx.x >> 3) << 4;
    const int tx0 = (blockIdx.x & 7) << 4;
    const unsigned short* xb = xh + (size_t)b * HW * 64;

    for (int i = tid; i < 2592; i += 512) {
        int hp = i >> 3, cq = i & 7;
        int hy = hp / 18, hx = hp - hy * 18;
        int gy = ty0 + hy - 1, gx = tx0 + hx - 1;
        u32x4 v = {0u, 0u, 0u, 0u};
        if ((unsigned)gy < 128u && (unsigned)gx < 128u)
            v = *(const u32x4*)(xb + (size_t)((gy << 7) + gx) * 64 + cq * 8);
        *(u32x4*)(sm + ((hp * 128 + cq * 16) ^ ((hp & 7) << 4)));
        *(u32x4*)(sm + ((hp * 128 + cq * 16) ^ ((hp & 7) << 4))) = v;
    }
    __syncthreads();

    const int lane = tid & 63;
    const int wv = tid >> 6;
    const int wm = wv & 1;                    // co-half
    const int wn = wv >> 1;                   // pixel-row group
    const int n = lane & 31;
    const int half = lane >> 5;
    const int px = n & 15;
    const int pyb = wn * 4 + (n >> 4);
    const int cobase = wm * 64;

    int hp0[2];
#pragma unroll
    for (int ni = 0; ni < 2; ++ni)
        hp0[ni] = (pyb + ni * 2) * 18 + px;

    f32x16 acc[2][2];
#pragma unroll
    for (int mi = 0; mi < 2; ++mi)
#pragma unroll
        for (int ni = 0; ni < 2; ++ni)
#pragma unroll
            for (int e = 0; e < 16; ++e) acc[mi][ni][e] = 0.f;

#pragma unroll
    for (int t9 = 0; t9 < 9; ++t9) {
        const int toff = (t9 / 3) * 18 + (t9 % 3);
#pragma unroll
        for (int kk = 0; kk < 4; ++kk) {
            bf16x8 a[2], bv[2];
#pragma unroll
            for (int mi = 0; mi < 2; ++mi)
                a[mi] = *(const bf16x8*)(wt +
                    (size_t)(t9 * 128 + cobase + mi * 32 + n) * 64 + kk * 16 + half * 8);
#pragma unroll
            for (int ni = 0; ni < 2; ++ni) {
                int hp = hp0[ni] + toff;
                bv[ni] = *(const bf16x8*)(sm + ((hp * 128 + kk * 32 + half * 16) ^ ((hp & 7) << 4)));
            }
#pragma unroll
            for (int mi = 0; mi < 2; ++mi)
#pragma unroll
                for (int ni = 0; ni < 2; ++ni)
                    acc[mi][ni] = __builtin_amdgcn_mfma_f32_32x32x16_bf16(
                        a[mi], bv[ni], acc[mi][ni], 0, 0, 0);
        }
    }

    // epilogue: CHW bf16.  D: col=lane&31 (pixel), row=r+8g+4*half (co)
    unsigned short* ob = outp + (size_t)b * 128 * HW;
#pragma unroll
    for (int ni = 0; ni < 2; ++ni) {
        int gp = (ty0 + pyb + ni * 2) * 128 + tx0 + px;
#pragma unroll
        for (int mi = 0; mi < 2; ++mi) {
            int cob = cobase + mi * 32 + half * 4;
#pragma unroll
            for (int g = 0; g < 4; ++g)
#pragma unroll
                for (int r = 0; r < 4; ++r)
                    ob[(size_t)(cob + g * 8 + r) * HW + gp] = f2b(acc[mi][ni][g * 4 + r]);
        }
    }
}

// ---------- fused deform + conv2, barrier-free K-loop ----------
// Offsets in CHW bf16: pair (oy,ox) for (ci,q) = uint at ch*HW + 2u,
// ch = 2ci + (q>>13), u = q&8191  (torch contiguous-view semantics).
__global__ __launch_bounds__(512, 4) void conv2_deform_kernel(
    const unsigned short* __restrict__ xh,    // bf16 HWC [b][p][64]
    const unsigned short* __restrict__ offs,  // bf16 CHW [b][128][HW]
    const unsigned short* __restrict__ wt,    // bf16 [9][64][64]
    const float* __restrict__ bias,
    float* __restrict__ out)
{
    __shared__ char sm[41472];
    const int tid = threadIdx.x;
    const int b = blockIdx.y;
    const int ty0 = (blockIdx.x >> 3) << 4;
    const int tx0 = (blockIdx.x & 7) << 4;
    const unsigned short* xb = xh + (size_t)b * HW * 64;
    const unsigned short* ob = offs + (size_t)b * 128 * HW;

    // deform the 18x18 halo x 64 ci into swizzled LDS
    auto deform_one = [&](int i) {
        int hp = i >> 6, ci = i & 63;
        int hy = hp / 18, hx = hp - hy * 18;
        int gy = ty0 + hy - 1, gx = tx0 + hx - 1;
        unsigned short val = 0;
        if ((unsigned)gy < 128u && (unsigned)gx < 128u) {
            int q = (gy << 7) + gx;
            int ch = 2 * ci + (q >> 13);
            int u = q & 8191;
            unsigned o2 = *(const unsigned*)(ob + (size_t)ch * HW + 2 * u);
            float oy = b2f((unsigned short)(o2 & 0xffffu));
            float ox = b2f((unsigned short)(o2 >> 16));
            float cy = fminf(fmaxf(oy + (float)gy, 0.f), 127.f);
            float cx = fminf(fmaxf(ox + (float)gx, 0.f), 127.f);
            float y0f = floorf(cy), x0f = floorf(cx);
            int y0 = (int)y0f, x0i = (int)x0f;
            int y1 = (int)ceilf(cy), x1 = (int)ceilf(cx);
            const unsigned short* pl = xb + ci;
            float v_lt = b2f(pl[(size_t)(y0 * 128 + x0i) * 64]);
            float v_rb = b2f(pl[(size_t)(y1 * 128 + x1) * 64]);
            float v_lb = b2f(pl[(size_t)(y0 * 128 + x1) * 64]);
            float v_rt = b2f(pl[(size_t)(y1 * 128 + x0i) * 64]);
            float dy = cy - y0f, dxf = cx - x0f;
            float v_t = fmaf(dy, v_rt - v_lt, v_lt);
            float v_b = fmaf(dy, v_rb - v_lb, v_lb);
            val = f2b(fmaf(dxf, v_b - v_t, v_t));
        }
        *(unsigned short*)(sm + ((hp * 128 + ci * 2) ^ ((hp & 7) << 4))) = val;
    };
#pragma unroll 4
    for (int k = 0; k < 40; ++k) deform_one(tid + k * 512);
    if (tid < 256) deform_one(tid + 40 * 512);     // 324*64 = 20736 total
    __syncthreads();

    const int lane = tid & 63;
    const int wv = tid >> 6;
    const int wm = wv & 1;
    const int wn = wv >> 1;
    const int n = lane & 31;
    const int half = lane >> 5;
    const int px = n & 15;
    const int pyb = wn * 4 + (n >> 4);
    const int cobase = wm * 32;

    int hp0[2];
#pragma unroll
    for (int ni = 0; ni < 2; ++ni)
        hp0[ni] = (pyb + ni * 2) * 18 + px;

    f32x16 acc[2];
#pragma unroll
    for (int ni = 0; ni < 2; ++ni)
#pragma unroll
        for (int e = 0; e < 16; ++e) acc[ni][e] = 0.f;

#pragma unroll
    for (int t9 = 0; t9 < 9; ++t9) {
        const int toff = (t9 / 3) * 18 + (t9 % 3);
#pragma unroll
        for (int kk = 0; kk < 4; ++kk) {
            bf16x8 a = *(const bf16x8*)(wt +
                (size_t)(t9 * 64 + cobase + n) * 64 + kk * 16 + half * 8);
            bf16x8 bv[2];
#pragma unroll
            for (int ni = 0; ni < 2; ++ni) {
                int hp = hp0[ni] + toff;
                bv[ni] = *(const bf16x8*)(sm + ((hp * 128 + kk * 32 + half * 16) ^ ((hp & 7) << 4)));
            }
#pragma unroll
            for (int ni = 0; ni < 2; ++ni)
                acc[ni] = __builtin_amdgcn_mfma_f32_32x32x16_bf16(
                    a, bv[ni], acc[ni], 0, 0, 0);
        }
    }

    // epilogue: fp32 NCHW + bias
#pragma unroll
    for (int ni = 0; ni < 2; ++ni) {
        int gp = (ty0 + pyb + ni * 2) * 128 + tx0 + px;
        float* o = out + (size_t)b * 64 * HW + gp;
        int cob = cobase + half * 4;
#pragma unroll
        for (int g = 0; g < 4; ++g)
#pragma unroll
            for (int r = 0; r < 4; ++r) {
                int co = cob + g * 8 + r;
                o[(size_t)co * HW] = acc[ni][g * 4 + r] + bias[co];
            }
    }
}

extern "C" void kernel_launch(void* const* d_in, const int* in_sizes, int n_in,
                              void* d_out, int out_size, void* d_ws, size_t ws_size,
                              hipStream_t stream) {
    const float* x      = (const float*)d_in[0];
    const float* W_off  = (const float*)d_in[1];
    const float* W_conv = (const float*)d_in[2];
    const float* b_conv = (const float*)d_in[3];

    unsigned short* xh   = (unsigned short*)d_ws;            // 16.8 MB
    unsigned short* offs = xh + (size_t)DB * HW * 64;        // 33.6 MB (CHW)
    unsigned short* wt1  = offs + (size_t)DB * HW * 128;     // 147 KB
    unsigned short* wt2  = wt1 + 9 * 128 * 64;               // 74 KB
    float* out = (float*)d_out;

    prep_kernel<<<2048 + 432, 256, 0, stream>>>(x, W_off, W_conv, xh, wt1, wt2);

    conv1_kernel<<<dim3(64, DB), 512, 0, stream>>>(xh, wt1, offs);

    conv2_deform_kernel<<<dim3(64, DB), 512, 0, stream>>>(
        xh, offs, wt2, b_conv, out);
}

// Round 9
// 188.959 us; speedup vs baseline: 1.1760x; 1.1760x over previous
//
#include <hip/hip_runtime.h>

#define DH 128
#define DW 128
#define DB 8
#define DC 64
constexpr int HW = DH * DW;

typedef __attribute__((ext_vector_type(4))) float f32x4;
typedef __attribute__((ext_vector_type(16))) float f32x16;
typedef __attribute__((ext_vector_type(8))) short bf16x8;
typedef __attribute__((ext_vector_type(4))) unsigned int u32x4;

__device__ __forceinline__ unsigned short f2b(float f) {
    unsigned int u = __builtin_bit_cast(unsigned int, f);
    u = (u + 0x7FFFu + ((u >> 16) & 1u)) >> 16;   // RNE
    return (unsigned short)u;
}
__device__ __forceinline__ float b2f(unsigned short h) {
    unsigned int u = ((unsigned int)h) << 16;
    return __builtin_bit_cast(float, u);
}

// ---------- prep: NCHW fp32 -> HWC bf16 transpose + weight repack ----------
// Weight layout: [tap][coblk][kk][half][co32][ci8], co=coblk*32+co32,
// ci = kk*16 + half*8 + ci8.  One A-fragment load = 1KB contiguous per wave.
__global__ __launch_bounds__(256) void prep_kernel(
    const float* __restrict__ x, const float* __restrict__ wo,
    const float* __restrict__ wc, unsigned short* __restrict__ xh,
    unsigned short* __restrict__ wt1, unsigned short* __restrict__ wt2)
{
    __shared__ unsigned short smx[64 * 80];
    const int blk = blockIdx.x;
    const int t = threadIdx.x;
    if (blk < 2048) {
        const int b = blk >> 8;
        const int p0 = (blk & 255) * 64;
        const int ci = t >> 2, q = t & 3;
        const float* xr = x + ((size_t)b * 64 + ci) * HW + p0;
#pragma unroll
        for (int j = 0; j < 4; ++j) {
            int pix = (j * 4 + q) * 4;
            float4 v = *(const float4*)(xr + pix);
            smx[(pix + 0) * 80 + ci] = f2b(v.x);
            smx[(pix + 1) * 80 + ci] = f2b(v.y);
            smx[(pix + 2) * 80 + ci] = f2b(v.z);
            smx[(pix + 3) * 80 + ci] = f2b(v.w);
        }
        __syncthreads();
        unsigned short* outp = xh + ((size_t)b * HW + p0) * 64;
        for (int i = t; i < 512; i += 256) {
            int pix = i >> 3, cq = i & 7;
            u32x4 v = *(const u32x4*)(smx + pix * 80 + cq * 8);
            *(u32x4*)(outp + pix * 64 + cq * 8) = v;
        }
    } else {
        int id = (blk - 2048) * 256 + t;
        const int N1 = 9 * 128 * 64, N2 = 9 * 64 * 64;
        if (id < N1) {
            int c8 = id & 7, r = id >> 3;
            int cr = r & 31; r >>= 5;
            int h = r & 1; r >>= 1;
            int kk = r & 3; r >>= 2;
            int cb = r & 3; int tp = r >> 2;
            int co = cb * 32 + cr, ci = kk * 16 + h * 8 + c8;
            wt1[id] = f2b(wo[(co * 64 + ci) * 9 + tp]);
        } else if (id < N1 + N2) {
            int k = id - N1;
            int c8 = k & 7, r = k >> 3;
            int cr = r & 31; r >>= 5;
            int h = r & 1; r >>= 1;
            int kk = r & 3; r >>= 2;
            int cb = r & 1; int tp = r >> 1;
            int co = cb * 32 + cr, ci = kk * 16 + h * 8 + c8;
            wt2[k] = f2b(wc[(co * 64 + ci) * 9 + tp]);
        }
    }
}

// ---------- conv1: 3x3 implicit GEMM, barrier-free K-loop ----------
// 512 thr = 8 waves, tile 16x16 px x 128 co. Halo in LDS (swz ^(hp&7)<<4);
// A-frags preloaded per tap from global (1KB/wave coalesced, L2-hot).
// ONE barrier total. Output: HWC bf16 uint2 stores (R6-proven epilogue).
__global__ __launch_bounds__(512, 4) void conv1_kernel(
    const unsigned short* __restrict__ xh,   // bf16 HWC [b][p][64]
    const unsigned short* __restrict__ wt,   // bf16 [9][4][4][2][32][8]
    unsigned short* __restrict__ outp)       // bf16 HWC [b][p][128]
{
    __shared__ char sm[41472];
    const int tid = threadIdx.x;
    const int b = blockIdx.y;
    const int ty0 = (blockIdx.x >> 3) << 4;
    const int tx0 = (blockIdx.x & 7) << 4;
    const unsigned short* xb = xh + (size_t)b * HW * 64;

    for (int i = tid; i < 2592; i += 512) {
        int hp = i >> 3, cq = i & 7;
        int hy = hp / 18, hx = hp - hy * 18;
        int gy = ty0 + hy - 1, gx = tx0 + hx - 1;
        u32x4 v = {0u, 0u, 0u, 0u};
        if ((unsigned)gy < 128u && (unsigned)gx < 128u)
            v = *(const u32x4*)(xb + (size_t)((gy << 7) + gx) * 64 + cq * 8);
        *(u32x4*)(sm + ((hp * 128 + cq * 16) ^ ((hp & 7) << 4))) = v;
    }
    __syncthreads();

    const int lane = tid & 63;
    const int wv = tid >> 6;
    const int wm = wv & 1;
    const int wn = wv >> 1;
    const int n = lane & 31;
    const int half = lane >> 5;
    const int px = n & 15;
    const int pyb = wn * 4 + (n >> 4);

    int hp0[2];
#pragma unroll
    for (int ni = 0; ni < 2; ++ni)
        hp0[ni] = (pyb + ni * 2) * 18 + px;

    f32x16 acc[2][2];
#pragma unroll
    for (int mi = 0; mi < 2; ++mi)
#pragma unroll
        for (int ni = 0; ni < 2; ++ni)
#pragma unroll
            for (int e = 0; e < 16; ++e) acc[mi][ni][e] = 0.f;

#pragma unroll
    for (int t9 = 0; t9 < 9; ++t9) {
        const int toff = (t9 / 3) * 18 + (t9 % 3);
        // preload this tap's A-fragments: 8 x 1KB/wave coalesced global loads
        bf16x8 a[2][4];
#pragma unroll
        for (int mi = 0; mi < 2; ++mi)
#pragma unroll
            for (int kk = 0; kk < 4; ++kk)
                a[mi][kk] = *(const bf16x8*)(wt +
                    (size_t)((((t9 * 4 + wm * 2 + mi) * 4 + kk) * 2 + half) * 32 + n) * 8);
#pragma unroll
        for (int kk = 0; kk < 4; ++kk) {
            bf16x8 bv[2];
#pragma unroll
            for (int ni = 0; ni < 2; ++ni) {
                int hp = hp0[ni] + toff;
                bv[ni] = *(const bf16x8*)(sm + ((hp * 128 + kk * 32 + half * 16) ^ ((hp & 7) << 4)));
            }
#pragma unroll
            for (int mi = 0; mi < 2; ++mi)
#pragma unroll
                for (int ni = 0; ni < 2; ++ni)
                    acc[mi][ni] = __builtin_amdgcn_mfma_f32_32x32x16_bf16(
                        a[mi][kk], bv[ni], acc[mi][ni], 0, 0, 0);
        }
    }

    // epilogue: HWC bf16. D: col=lane&31 (pixel), row=(r&3)+8*(r>>2)+4*half (co)
#pragma unroll
    for (int ni = 0; ni < 2; ++ni) {
        int gp = (ty0 + pyb + ni * 2) * 128 + tx0 + px;
        unsigned short* o = outp + ((size_t)b * HW + gp) * 128;
#pragma unroll
        for (int mi = 0; mi < 2; ++mi) {
            int cob = wm * 64 + mi * 32 + half * 4;
#pragma unroll
            for (int g = 0; g < 4; ++g) {
                uint2 pk;
                pk.x = (unsigned)f2b(acc[mi][ni][g * 4 + 0]) |
                       ((unsigned)f2b(acc[mi][ni][g * 4 + 1]) << 16);
                pk.y = (unsigned)f2b(acc[mi][ni][g * 4 + 2]) |
                       ((unsigned)f2b(acc[mi][ni][g * 4 + 3]) << 16);
                *(uint2*)(o + cob + g * 8) = pk;
            }
        }
    }
}

// ---------- fused deform + conv2, barrier-free K-loop ----------
// Offsets HWC bf16 [b][p][128] (R7-proven coalesced read): for (ci,q):
// ch = 2ci + (q>>13), pp = (2q)&16383; oy at [pp][ch], ox at [pp+1][ch].
__global__ __launch_bounds__(512, 4) void conv2_deform_kernel(
    const unsigned short* __restrict__ xh,    // bf16 HWC [b][p][64]
    const unsigned short* __restrict__ offs,  // bf16 HWC [b][p][128]
    const unsigned short* __restrict__ wt,    // bf16 [9][2][4][2][32][8]
    const float* __restrict__ bias,
    float* __restrict__ out)
{
    __shared__ char sm[41472];
    const int tid = threadIdx.x;
    const int b = blockIdx.y;
    const int ty0 = (blockIdx.x >> 3) << 4;
    const int tx0 = (blockIdx.x & 7) << 4;
    const unsigned short* xb = xh + (size_t)b * HW * 64;
    const unsigned short* ob = offs + (size_t)b * HW * 128;

    auto deform_one = [&](int i) {
        int hp = i >> 6, ci = i & 63;
        int hy = hp / 18, hx = hp - hy * 18;
        int gy = ty0 + hy - 1, gx = tx0 + hx - 1;
        unsigned short val = 0;
        if ((unsigned)gy < 128u && (unsigned)gx < 128u) {
            int q = (gy << 7) + gx;
            int ch = 2 * ci + (q >> 13);
            int pp = (2 * q) & (HW - 1);
            float oy = b2f(ob[(size_t)pp * 128 + ch]);
            float ox = b2f(ob[(size_t)(pp + 1) * 128 + ch]);
            float cy = fminf(fmaxf(oy + (float)gy, 0.f), 127.f);
            float cx = fminf(fmaxf(ox + (float)gx, 0.f), 127.f);
            float y0f = floorf(cy), x0f = floorf(cx);
            int y0 = (int)y0f, x0i = (int)x0f;
            int y1 = (int)ceilf(cy), x1 = (int)ceilf(cx);
            const unsigned short* pl = xb + ci;
            float v_lt = b2f(pl[(size_t)(y0 * 128 + x0i) * 64]);
            float v_rb = b2f(pl[(size_t)(y1 * 128 + x1) * 64]);
            float v_lb = b2f(pl[(size_t)(y0 * 128 + x1) * 64]);
            float v_rt = b2f(pl[(size_t)(y1 * 128 + x0i) * 64]);
            float dy = cy - y0f, dxf = cx - x0f;
            float v_t = fmaf(dy, v_rt - v_lt, v_lt);
            float v_b = fmaf(dy, v_rb - v_lb, v_lb);
            val = f2b(fmaf(dxf, v_b - v_t, v_t));
        }
        *(unsigned short*)(sm + ((hp * 128 + ci * 2) ^ ((hp & 7) << 4))) = val;
    };
#pragma unroll 4
    for (int k = 0; k < 40; ++k) deform_one(tid + k * 512);
    if (tid < 256) deform_one(tid + 40 * 512);     // 324*64 = 20736 total
    __syncthreads();

    const int lane = tid & 63;
    const int wv = tid >> 6;
    const int wm = wv & 1;
    const int wn = wv >> 1;
    const int n = lane & 31;
    const int half = lane >> 5;
    const int px = n & 15;
    const int pyb = wn * 4 + (n >> 4);

    int hp0[2];
#pragma unroll
    for (int ni = 0; ni < 2; ++ni)
        hp0[ni] = (pyb + ni * 2) * 18 + px;

    f32x16 acc[2];
#pragma unroll
    for (int ni = 0; ni < 2; ++ni)
#pragma unroll
        for (int e = 0; e < 16; ++e) acc[ni][e] = 0.f;

#pragma unroll
    for (int t9 = 0; t9 < 9; ++t9) {
        const int toff = (t9 / 3) * 18 + (t9 % 3);
        bf16x8 a[4];
#pragma unroll
        for (int kk = 0; kk < 4; ++kk)
            a[kk] = *(const bf16x8*)(wt +
                (size_t)((((t9 * 2 + wm) * 4 + kk) * 2 + half) * 32 + n) * 8);
#pragma unroll
        for (int kk = 0; kk < 4; ++kk) {
            bf16x8 bv[2];
#pragma unroll
            for (int ni = 0; ni < 2; ++ni) {
                int hp = hp0[ni] + toff;
                bv[ni] = *(const bf16x8*)(sm + ((hp * 128 + kk * 32 + half * 16) ^ ((hp & 7) << 4)));
            }
#pragma unroll
            for (int ni = 0; ni < 2; ++ni)
                acc[ni] = __builtin_amdgcn_mfma_f32_32x32x16_bf16(
                    a[kk], bv[ni], acc[ni], 0, 0, 0);
        }
    }

    // epilogue: fp32 NCHW + bias
#pragma unroll
    for (int ni = 0; ni < 2; ++ni) {
        int gp = (ty0 + pyb + ni * 2) * 128 + tx0 + px;
        float* o = out + (size_t)b * 64 * HW + gp;
        int cob = wm * 32 + half * 4;
#pragma unroll
        for (int g = 0; g < 4; ++g)
#pragma unroll
            for (int r = 0; r < 4; ++r) {
                int co = cob + g * 8 + r;
                o[(size_t)co * HW] = acc[ni][g * 4 + r] + bias[co];
            }
    }
}

extern "C" void kernel_launch(void* const* d_in, const int* in_sizes, int n_in,
                              void* d_out, int out_size, void* d_ws, size_t ws_size,
                              hipStream_t stream) {
    const float* x      = (const float*)d_in[0];
    const float* W_off  = (const float*)d_in[1];
    const float* W_conv = (const float*)d_in[2];
    const float* b_conv = (const float*)d_in[3];

    unsigned short* xh   = (unsigned short*)d_ws;            // 16.8 MB
    unsigned short* offs = xh + (size_t)DB * HW * 64;        // 33.6 MB (HWC)
    unsigned short* wt1  = offs + (size_t)DB * HW * 128;     // 147 KB
    unsigned short* wt2  = wt1 + 9 * 128 * 64;               // 74 KB
    float* out = (float*)d_out;

    prep_kernel<<<2048 + 432, 256, 0, stream>>>(x, W_off, W_conv, xh, wt1, wt2);

    conv1_kernel<<<dim3(64, DB), 512, 0, stream>>>(xh, wt1, offs);

    conv2_deform_kernel<<<dim3(64, DB), 512, 0, stream>>>(
        xh, offs, wt2, b_conv, out);
}

// Round 10
// 183.094 us; speedup vs baseline: 1.2137x; 1.0320x over previous
//
#include <hip/hip_runtime.h>

#define DH 128
#define DW 128
#define DB 8
#define DC 64
constexpr int HW = DH * DW;

typedef __attribute__((ext_vector_type(4))) float f32x4;
typedef __attribute__((ext_vector_type(16))) float f32x16;
typedef __attribute__((ext_vector_type(8))) short bf16x8;
typedef __attribute__((ext_vector_type(4))) unsigned int u32x4;

__device__ __forceinline__ unsigned short f2b(float f) {
    unsigned int u = __builtin_bit_cast(unsigned int, f);
    u = (u + 0x7FFFu + ((u >> 16) & 1u)) >> 16;   // RNE
    return (unsigned short)u;
}
__device__ __forceinline__ float b2f(unsigned short h) {
    unsigned int u = ((unsigned int)h) << 16;
    return __builtin_bit_cast(float, u);
}

// ---------- prep: NCHW fp32 -> HWC bf16 transpose + weight repack ----------
// Weight layout: [tap][coblk][kk][half][co32][ci8], co=coblk*32+co32,
// ci = kk*16 + half*8 + ci8.  One B-fragment load = 1KB contiguous per wave.
__global__ __launch_bounds__(256) void prep_kernel(
    const float* __restrict__ x, const float* __restrict__ wo,
    const float* __restrict__ wc, unsigned short* __restrict__ xh,
    unsigned short* __restrict__ wt1, unsigned short* __restrict__ wt2)
{
    __shared__ unsigned short smx[64 * 80];
    const int blk = blockIdx.x;
    const int t = threadIdx.x;
    if (blk < 2048) {
        const int b = blk >> 8;
        const int p0 = (blk & 255) * 64;
        const int ci = t >> 2, q = t & 3;
        const float* xr = x + ((size_t)b * 64 + ci) * HW + p0;
#pragma unroll
        for (int j = 0; j < 4; ++j) {
            int pix = (j * 4 + q) * 4;
            float4 v = *(const float4*)(xr + pix);
            smx[(pix + 0) * 80 + ci] = f2b(v.x);
            smx[(pix + 1) * 80 + ci] = f2b(v.y);
            smx[(pix + 2) * 80 + ci] = f2b(v.z);
            smx[(pix + 3) * 80 + ci] = f2b(v.w);
        }
        __syncthreads();
        unsigned short* outp = xh + ((size_t)b * HW + p0) * 64;
        for (int i = t; i < 512; i += 256) {
            int pix = i >> 3, cq = i & 7;
            u32x4 v = *(const u32x4*)(smx + pix * 80 + cq * 8);
            *(u32x4*)(outp + pix * 64 + cq * 8) = v;
        }
    } else {
        int id = (blk - 2048) * 256 + t;
        const int N1 = 9 * 128 * 64, N2 = 9 * 64 * 64;
        if (id < N1) {
            int c8 = id & 7, r = id >> 3;
            int cr = r & 31; r >>= 5;
            int h = r & 1; r >>= 1;
            int kk = r & 3; r >>= 2;
            int cb = r & 3; int tp = r >> 2;
            int co = cb * 32 + cr, ci = kk * 16 + h * 8 + c8;
            wt1[id] = f2b(wo[(co * 64 + ci) * 9 + tp]);
        } else if (id < N1 + N2) {
            int k = id - N1;
            int c8 = k & 7, r = k >> 3;
            int cr = r & 31; r >>= 5;
            int h = r & 1; r >>= 1;
            int kk = r & 3; r >>= 2;
            int cb = r & 1; int tp = r >> 1;
            int co = cb * 32 + cr, ci = kk * 16 + h * 8 + c8;
            wt2[k] = f2b(wc[(co * 64 + ci) * 9 + tp]);
        }
    }
}

// ---------- conv1: 3x3 implicit GEMM, SWAPPED operands ----------
// A = pixels (LDS halo), B = weights (global, coalesced 1KB/wave).
// D: col(lane&31) = CHANNEL -> every store instruction writes full 64B
// lines in the HWC output. Wave (wq,wc): 4 pixel rows x 64 channels,
// acc[2 pixel-groups][2 co-groups]. ONE barrier total.
__global__ __launch_bounds__(512, 4) void conv1_kernel(
    const unsigned short* __restrict__ xh,   // bf16 HWC [b][p][64]
    const unsigned short* __restrict__ wt,   // bf16 [9][4][4][2][32][8]
    unsigned short* __restrict__ outp)       // bf16 HWC [b][p][128]
{
    __shared__ char sm[41472];
    const int tid = threadIdx.x;
    const int b = blockIdx.y;
    const int ty0 = (blockIdx.x >> 3) << 4;
    const int tx0 = (blockIdx.x & 7) << 4;
    const unsigned short* xb = xh + (size_t)b * HW * 64;

    for (int i = tid; i < 2592; i += 512) {
        int hp = i >> 3, cq = i & 7;
        int hy = hp / 18, hx = hp - hy * 18;
        int gy = ty0 + hy - 1, gx = tx0 + hx - 1;
        u32x4 v = {0u, 0u, 0u, 0u};
        if ((unsigned)gy < 128u && (unsigned)gx < 128u)
            v = *(const u32x4*)(xb + (size_t)((gy << 7) + gx) * 64 + cq * 8);
        *(u32x4*)(sm + ((hp * 128 + cq * 16) ^ ((hp & 7) << 4))) = v;
    }
    __syncthreads();

    const int lane = tid & 63;
    const int wv = tid >> 6;
    const int wq = wv & 3;        // pixel quad: rows wq*4..wq*4+3
    const int wc = wv >> 2;       // channel half: co 64*wc..+63
    const int n = lane & 31;
    const int half = lane >> 5;
    const int px = n & 15;
    const int pyb = wq * 4 + (n >> 4);

    int hp0[2];
#pragma unroll
    for (int pi = 0; pi < 2; ++pi)
        hp0[pi] = (pyb + pi * 2) * 18 + px;

    f32x16 acc[2][2];
#pragma unroll
    for (int pi = 0; pi < 2; ++pi)
#pragma unroll
        for (int cj = 0; cj < 2; ++cj)
#pragma unroll
            for (int e = 0; e < 16; ++e) acc[pi][cj][e] = 0.f;

#pragma unroll
    for (int t9 = 0; t9 < 9; ++t9) {
        const int toff = (t9 / 3) * 18 + (t9 % 3);
        // preload this tap's B-fragments (weights): 8 x 1KB/wave coalesced
        bf16x8 w[2][4];
#pragma unroll
        for (int cj = 0; cj < 2; ++cj)
#pragma unroll
            for (int kk = 0; kk < 4; ++kk)
                w[cj][kk] = *(const bf16x8*)(wt +
                    (size_t)((((t9 * 4 + wc * 2 + cj) * 4 + kk) * 2 + half) * 32 + n) * 8);
#pragma unroll
        for (int kk = 0; kk < 4; ++kk) {
            bf16x8 a[2];
#pragma unroll
            for (int pi = 0; pi < 2; ++pi) {
                int hp = hp0[pi] + toff;
                a[pi] = *(const bf16x8*)(sm + ((hp * 128 + kk * 32 + half * 16) ^ ((hp & 7) << 4)));
            }
#pragma unroll
            for (int pi = 0; pi < 2; ++pi)
#pragma unroll
                for (int cj = 0; cj < 2; ++cj)
                    acc[pi][cj] = __builtin_amdgcn_mfma_f32_32x32x16_bf16(
                        a[pi], w[cj][kk], acc[pi][cj], 0, 0, 0);
        }
    }

    // epilogue: D col=lane&31 = co-in-group, row r' = (r&3)+8*(r>>2)+4*half
    // = pixel m in [0,32). Lanes n=0..31 -> 32 contiguous channels = 64B line.
    unsigned short* obp = outp + (size_t)b * HW * 128;
#pragma unroll
    for (int pi = 0; pi < 2; ++pi)
#pragma unroll
        for (int cj = 0; cj < 2; ++cj) {
            int cob = (wc * 2 + cj) * 32 + n;
#pragma unroll
            for (int r = 0; r < 16; ++r) {
                int m = (r & 3) + 8 * (r >> 2) + 4 * half;
                int py = wq * 4 + pi * 2 + (m >> 4);
                int gp = (ty0 + py) * 128 + tx0 + (m & 15);
                obp[(size_t)gp * 128 + cob] = f2b(acc[pi][cj][r]);
            }
        }
}

// ---------- fused deform + conv2, barrier-free K-loop (unchanged R9) ----------
__global__ __launch_bounds__(512, 4) void conv2_deform_kernel(
    const unsigned short* __restrict__ xh,    // bf16 HWC [b][p][64]
    const unsigned short* __restrict__ offs,  // bf16 HWC [b][p][128]
    const unsigned short* __restrict__ wt,    // bf16 [9][2][4][2][32][8]
    const float* __restrict__ bias,
    float* __restrict__ out)
{
    __shared__ char sm[41472];
    const int tid = threadIdx.x;
    const int b = blockIdx.y;
    const int ty0 = (blockIdx.x >> 3) << 4;
    const int tx0 = (blockIdx.x & 7) << 4;
    const unsigned short* xb = xh + (size_t)b * HW * 64;
    const unsigned short* ob = offs + (size_t)b * HW * 128;

    auto deform_one = [&](int i) {
        int hp = i >> 6, ci = i & 63;
        int hy = hp / 18, hx = hp - hy * 18;
        int gy = ty0 + hy - 1, gx = tx0 + hx - 1;
        unsigned short val = 0;
        if ((unsigned)gy < 128u && (unsigned)gx < 128u) {
            int q = (gy << 7) + gx;
            int ch = 2 * ci + (q >> 13);
            int pp = (2 * q) & (HW - 1);
            float oy = b2f(ob[(size_t)pp * 128 + ch]);
            float ox = b2f(ob[(size_t)(pp + 1) * 128 + ch]);
            float cy = fminf(fmaxf(oy + (float)gy, 0.f), 127.f);
            float cx = fminf(fmaxf(ox + (float)gx, 0.f), 127.f);
            float y0f = floorf(cy), x0f = floorf(cx);
            int y0 = (int)y0f, x0i = (int)x0f;
            int y1 = (int)ceilf(cy), x1 = (int)ceilf(cx);
            const unsigned short* pl = xb + ci;
            float v_lt = b2f(pl[(size_t)(y0 * 128 + x0i) * 64]);
            float v_rb = b2f(pl[(size_t)(y1 * 128 + x1) * 64]);
            float v_lb = b2f(pl[(size_t)(y0 * 128 + x1) * 64]);
            float v_rt = b2f(pl[(size_t)(y1 * 128 + x0i) * 64]);
            float dy = cy - y0f, dxf = cx - x0f;
            float v_t = fmaf(dy, v_rt - v_lt, v_lt);
            float v_b = fmaf(dy, v_rb - v_lb, v_lb);
            val = f2b(fmaf(dxf, v_b - v_t, v_t));
        }
        *(unsigned short*)(sm + ((hp * 128 + ci * 2) ^ ((hp & 7) << 4))) = val;
    };
#pragma unroll 4
    for (int k = 0; k < 40; ++k) deform_one(tid + k * 512);
    if (tid < 256) deform_one(tid + 40 * 512);     // 324*64 = 20736 total
    __syncthreads();

    const int lane = tid & 63;
    const int wv = tid >> 6;
    const int wm = wv & 1;
    const int wn = wv >> 1;
    const int n = lane & 31;
    const int half = lane >> 5;
    const int px = n & 15;
    const int pyb = wn * 4 + (n >> 4);

    int hp0[2];
#pragma unroll
    for (int ni = 0; ni < 2; ++ni)
        hp0[ni] = (pyb + ni * 2) * 18 + px;

    f32x16 acc[2];
#pragma unroll
    for (int ni = 0; ni < 2; ++ni)
#pragma unroll
        for (int e = 0; e < 16; ++e) acc[ni][e] = 0.f;

#pragma unroll
    for (int t9 = 0; t9 < 9; ++t9) {
        const int toff = (t9 / 3) * 18 + (t9 % 3);
        bf16x8 a[4];
#pragma unroll
        for (int kk = 0; kk < 4; ++kk)
            a[kk] = *(const bf16x8*)(wt +
                (size_t)((((t9 * 2 + wm) * 4 + kk) * 2 + half) * 32 + n) * 8);
#pragma unroll
        for (int kk = 0; kk < 4; ++kk) {
            bf16x8 bv[2];
#pragma unroll
            for (int ni = 0; ni < 2; ++ni) {
                int hp = hp0[ni] + toff;
                bv[ni] = *(const bf16x8*)(sm + ((hp * 128 + kk * 32 + half * 16) ^ ((hp & 7) << 4)));
            }
#pragma unroll
            for (int ni = 0; ni < 2; ++ni)
                acc[ni] = __builtin_amdgcn_mfma_f32_32x32x16_bf16(
                    a[kk], bv[ni], acc[ni], 0, 0, 0);
        }
    }

    // epilogue: fp32 NCHW + bias (lanes span pixels -> full 64B lines)
#pragma unroll
    for (int ni = 0; ni < 2; ++ni) {
        int gp = (ty0 + pyb + ni * 2) * 128 + tx0 + px;
        float* o = out + (size_t)b * 64 * HW + gp;
        int cob = wm * 32 + half * 4;
#pragma unroll
        for (int g = 0; g < 4; ++g)
#pragma unroll
            for (int r = 0; r < 4; ++r) {
                int co = cob + g * 8 + r;
                o[(size_t)co * HW] = acc[ni][g * 4 + r] + bias[co];
            }
    }
}

extern "C" void kernel_launch(void* const* d_in, const int* in_sizes, int n_in,
                              void* d_out, int out_size, void* d_ws, size_t ws_size,
                              hipStream_t stream) {
    const float* x      = (const float*)d_in[0];
    const float* W_off  = (const float*)d_in[1];
    const float* W_conv = (const float*)d_in[2];
    const float* b_conv = (const float*)d_in[3];

    unsigned short* xh   = (unsigned short*)d_ws;            // 16.8 MB
    unsigned short* offs = xh + (size_t)DB * HW * 64;        // 33.6 MB (HWC)
    unsigned short* wt1  = offs + (size_t)DB * HW * 128;     // 147 KB
    unsigned short* wt2  = wt1 + 9 * 128 * 64;               // 74 KB
    float* out = (float*)d_out;

    prep_kernel<<<2048 + 432, 256, 0, stream>>>(x, W_off, W_conv, xh, wt1, wt2);

    conv1_kernel<<<dim3(64, DB), 512, 0, stream>>>(xh, wt1, offs);

    conv2_deform_kernel<<<dim3(64, DB), 512, 0, stream>>>(
        xh, offs, wt2, b_conv, out);
}

// Round 11
// 164.064 us; speedup vs baseline: 1.3544x; 1.1160x over previous
//
#include <hip/hip_runtime.h>

#define DH 128
#define DW 128
#define DB 8
#define DC 64
constexpr int HW = DH * DW;

typedef __attribute__((ext_vector_type(4))) float f32x4;
typedef __attribute__((ext_vector_type(16))) float f32x16;
typedef __attribute__((ext_vector_type(8))) short bf16x8;
typedef __attribute__((ext_vector_type(4))) unsigned int u32x4;

__device__ __forceinline__ unsigned short f2b(float f) {
    unsigned int u = __builtin_bit_cast(unsigned int, f);
    u = (u + 0x7FFFu + ((u >> 16) & 1u)) >> 16;   // RNE
    return (unsigned short)u;
}
__device__ __forceinline__ float b2f(unsigned short h) {
    unsigned int u = ((unsigned int)h) << 16;
    return __builtin_bit_cast(float, u);
}

// ---------- prep: NCHW fp32 -> HWC bf16 transpose + weight repack ----------
// Weight layout: [tap][coblk][kk][half][co32][ci8], co=coblk*32+co32,
// ci = kk*16 + half*8 + ci8.  One B-fragment load = 1KB contiguous per wave.
__global__ __launch_bounds__(256) void prep_kernel(
    const float* __restrict__ x, const float* __restrict__ wo,
    const float* __restrict__ wc, unsigned short* __restrict__ xh,
    unsigned short* __restrict__ wt1, unsigned short* __restrict__ wt2)
{
    __shared__ unsigned short smx[64 * 80];
    const int blk = blockIdx.x;
    const int t = threadIdx.x;
    if (blk < 2048) {
        const int b = blk >> 8;
        const int p0 = (blk & 255) * 64;
        const int ci = t >> 2, q = t & 3;
        const float* xr = x + ((size_t)b * 64 + ci) * HW + p0;
#pragma unroll
        for (int j = 0; j < 4; ++j) {
            int pix = (j * 4 + q) * 4;
            float4 v = *(const float4*)(xr + pix);
            smx[(pix + 0) * 80 + ci] = f2b(v.x);
            smx[(pix + 1) * 80 + ci] = f2b(v.y);
            smx[(pix + 2) * 80 + ci] = f2b(v.z);
            smx[(pix + 3) * 80 + ci] = f2b(v.w);
        }
        __syncthreads();
        unsigned short* outp = xh + ((size_t)b * HW + p0) * 64;
        for (int i = t; i < 512; i += 256) {
            int pix = i >> 3, cq = i & 7;
            u32x4 v = *(const u32x4*)(smx + pix * 80 + cq * 8);
            *(u32x4*)(outp + pix * 64 + cq * 8) = v;
        }
    } else {
        int id = (blk - 2048) * 256 + t;
        const int N1 = 9 * 128 * 64, N2 = 9 * 64 * 64;
        if (id < N1) {
            int c8 = id & 7, r = id >> 3;
            int cr = r & 31; r >>= 5;
            int h = r & 1; r >>= 1;
            int kk = r & 3; r >>= 2;
            int cb = r & 3; int tp = r >> 2;
            int co = cb * 32 + cr, ci = kk * 16 + h * 8 + c8;
            wt1[id] = f2b(wo[(co * 64 + ci) * 9 + tp]);
        } else if (id < N1 + N2) {
            int k = id - N1;
            int c8 = k & 7, r = k >> 3;
            int cr = r & 31; r >>= 5;
            int h = r & 1; r >>= 1;
            int kk = r & 3; r >>= 2;
            int cb = r & 1; int tp = r >> 1;
            int co = cb * 32 + cr, ci = kk * 16 + h * 8 + c8;
            wt2[k] = f2b(wc[(co * 64 + ci) * 9 + tp]);
        }
    }
}

// ---------- conv1: 3x3 implicit GEMM, swapped operands ----------
// A = pixels (LDS halo), B = weights (global, coalesced 1KB/wave).
// Epilogue: stage output tile through LDS (2 x 32KB phases), emit the
// deform-friendly layout offs_u32[b][q][ci] = (oy,ox) packed, with every
// wave store = 256B contiguous run (full lines, no RMW).
__global__ __launch_bounds__(512, 4) void conv1_kernel(
    const unsigned short* __restrict__ xh,   // bf16 HWC [b][p][64]
    const unsigned short* __restrict__ wt,   // bf16 [9][4][4][2][32][8]
    unsigned int* __restrict__ offsu)        // u32 [b][HW q][64 ci]
{
    __shared__ char sm[41472];
    const int tid = threadIdx.x;
    const int b = blockIdx.y;
    const int ty0 = (blockIdx.x >> 3) << 4;
    const int tx0 = (blockIdx.x & 7) << 4;
    const unsigned short* xb = xh + (size_t)b * HW * 64;

    for (int i = tid; i < 2592; i += 512) {
        int hp = i >> 3, cq = i & 7;
        int hy = hp / 18, hx = hp - hy * 18;
        int gy = ty0 + hy - 1, gx = tx0 + hx - 1;
        u32x4 v = {0u, 0u, 0u, 0u};
        if ((unsigned)gy < 128u && (unsigned)gx < 128u)
            v = *(const u32x4*)(xb + (size_t)((gy << 7) + gx) * 64 + cq * 8);
        *(u32x4*)(sm + ((hp * 128 + cq * 16) ^ ((hp & 7) << 4))) = v;
    }
    __syncthreads();

    const int lane = tid & 63;
    const int wv = tid >> 6;
    const int wq = wv & 3;        // pixel quad: rows wq*4..wq*4+3
    const int wc = wv >> 2;       // channel half: co 64*wc..+63
    const int n = lane & 31;
    const int half = lane >> 5;
    const int px = n & 15;
    const int pyb = wq * 4 + (n >> 4);

    int hp0[2];
#pragma unroll
    for (int pi = 0; pi < 2; ++pi)
        hp0[pi] = (pyb + pi * 2) * 18 + px;

    f32x16 acc[2][2];
#pragma unroll
    for (int pi = 0; pi < 2; ++pi)
#pragma unroll
        for (int cj = 0; cj < 2; ++cj)
#pragma unroll
            for (int e = 0; e < 16; ++e) acc[pi][cj][e] = 0.f;

#pragma unroll
    for (int t9 = 0; t9 < 9; ++t9) {
        const int toff = (t9 / 3) * 18 + (t9 % 3);
        bf16x8 w[2][4];
#pragma unroll
        for (int cj = 0; cj < 2; ++cj)
#pragma unroll
            for (int kk = 0; kk < 4; ++kk)
                w[cj][kk] = *(const bf16x8*)(wt +
                    (size_t)((((t9 * 4 + wc * 2 + cj) * 4 + kk) * 2 + half) * 32 + n) * 8);
#pragma unroll
        for (int kk = 0; kk < 4; ++kk) {
            bf16x8 a[2];
#pragma unroll
            for (int pi = 0; pi < 2; ++pi) {
                int hp = hp0[pi] + toff;
                a[pi] = *(const bf16x8*)(sm + ((hp * 128 + kk * 32 + half * 16) ^ ((hp & 7) << 4)));
            }
#pragma unroll
            for (int pi = 0; pi < 2; ++pi)
#pragma unroll
                for (int cj = 0; cj < 2; ++cj)
                    acc[pi][cj] = __builtin_amdgcn_mfma_f32_32x32x16_bf16(
                        a[pi], w[cj][kk], acc[pi][cj], 0, 0, 0);
        }
    }

    // ---- epilogue through LDS, 2 phases of 8 pixel rows (32KB each) ----
    // LDS element ((py8*8+pp)*256 + ch*2 + s): rows of 8 pixel-pairs,
    // 128 channels x 2 pixels-in-pair.  D: col=lane&31 -> channel,
    // row m=(r&3)+8*(r>>2)+4*half -> pixel; pixel row = wq*4+pi*2+(m>>4).
    __syncthreads();   // all halo reads done; sm is reusable
    unsigned int* ou = offsu + (size_t)b * HW * 64;
#pragma unroll
    for (int ph = 0; ph < 2; ++ph) {
        if ((wq >> 1) == ph) {
#pragma unroll
            for (int pi = 0; pi < 2; ++pi)
#pragma unroll
                for (int cj = 0; cj < 2; ++cj) {
                    int ch = (wc * 2 + cj) * 32 + n;
#pragma unroll
                    for (int r = 0; r < 16; ++r) {
                        int m = (r & 3) + 8 * (r >> 2) + 4 * half;
                        int py8 = (wq & 1) * 4 + pi * 2 + (m >> 4);
                        int pxx = m & 15;
                        int idx = (py8 * 8 + (pxx >> 1)) * 256 + ch * 2 + (pxx & 1);
                        *(unsigned short*)(sm + idx * 2) = f2b(acc[pi][cj][r]);
                    }
                }
        }
        __syncthreads();
        // store 8192 uints; per wave: 256B contiguous global runs
#pragma unroll
        for (int j = 0; j < 16; ++j) {
            int f = j * 512 + tid;
            int py = f >> 10, hi = (f >> 9) & 1, pp = (f >> 6) & 7, ci = f & 63;
            unsigned v = *(unsigned*)(sm + (py * 8 + pp) * 512 + (2 * ci + hi) * 4);
            int q = hi * 8192 + (ty0 + ph * 8 + py) * 64 + (tx0 >> 1) + pp;
            ou[(size_t)q * 64 + ci] = v;
        }
        if (ph == 0) __syncthreads();
    }
}

// ---------- fused deform + conv2 ----------
// Offsets u32 [b][q][ci]: uint at (b*HW+q)*64+ci packs (oy,ox) for channel
// ci at source pixel q -> ONE coalesced 4B load (256B/wave).
__global__ __launch_bounds__(512, 4) void conv2_deform_kernel(
    const unsigned short* __restrict__ xh,    // bf16 HWC [b][p][64]
    const unsigned int* __restrict__ offsu,   // u32 [b][q][64]
    const unsigned short* __restrict__ wt,    // bf16 [9][2][4][2][32][8]
    const float* __restrict__ bias,
    float* __restrict__ out)
{
    __shared__ char sm[41472];
    const int tid = threadIdx.x;
    const int b = blockIdx.y;
    const int ty0 = (blockIdx.x >> 3) << 4;
    const int tx0 = (blockIdx.x & 7) << 4;
    const unsigned short* xb = xh + (size_t)b * HW * 64;
    const unsigned int* obu = offsu + (size_t)b * HW * 64;

    auto deform_one = [&](int i) {
        int hp = i >> 6, ci = i & 63;
        int hy = hp / 18, hx = hp - hy * 18;
        int gy = ty0 + hy - 1, gx = tx0 + hx - 1;
        unsigned short val = 0;
        if ((unsigned)gy < 128u && (unsigned)gx < 128u) {
            int q = (gy << 7) + gx;
            unsigned o2 = obu[(size_t)q * 64 + ci];
            float oy = b2f((unsigned short)(o2 & 0xffffu));
            float ox = b2f((unsigned short)(o2 >> 16));
            float cy = fminf(fmaxf(oy + (float)gy, 0.f), 127.f);
            float cx = fminf(fmaxf(ox + (float)gx, 0.f), 127.f);
            float y0f = floorf(cy), x0f = floorf(cx);
            int y0 = (int)y0f, x0i = (int)x0f;
            int y1 = (int)ceilf(cy), x1 = (int)ceilf(cx);
            const unsigned short* pl = xb + ci;
            float v_lt = b2f(pl[(size_t)(y0 * 128 + x0i) * 64]);
            float v_rb = b2f(pl[(size_t)(y1 * 128 + x1) * 64]);
            float v_lb = b2f(pl[(size_t)(y0 * 128 + x1) * 64]);
            float v_rt = b2f(pl[(size_t)(y1 * 128 + x0i) * 64]);
            float dy = cy - y0f, dxf = cx - x0f;
            float v_t = fmaf(dy, v_rt - v_lt, v_lt);
            float v_b = fmaf(dy, v_rb - v_lb, v_lb);
            val = f2b(fmaf(dxf, v_b - v_t, v_t));
        }
        *(unsigned short*)(sm + ((hp * 128 + ci * 2) ^ ((hp & 7) << 4))) = val;
    };
#pragma unroll 4
    for (int k = 0; k < 40; ++k) deform_one(tid + k * 512);
    if (tid < 256) deform_one(tid + 40 * 512);     // 324*64 = 20736 total
    __syncthreads();

    const int lane = tid & 63;
    const int wv = tid >> 6;
    const int wm = wv & 1;
    const int wn = wv >> 1;
    const int n = lane & 31;
    const int half = lane >> 5;
    const int px = n & 15;
    const int pyb = wn * 4 + (n >> 4);

    int hp0[2];
#pragma unroll
    for (int ni = 0; ni < 2; ++ni)
        hp0[ni] = (pyb + ni * 2) * 18 + px;

    f32x16 acc[2];
#pragma unroll
    for (int ni = 0; ni < 2; ++ni)
#pragma unroll
        for (int e = 0; e < 16; ++e) acc[ni][e] = 0.f;

#pragma unroll
    for (int t9 = 0; t9 < 9; ++t9) {
        const int toff = (t9 / 3) * 18 + (t9 % 3);
        bf16x8 a[4];
#pragma unroll
        for (int kk = 0; kk < 4; ++kk)
            a[kk] = *(const bf16x8*)(wt +
                (size_t)((((t9 * 2 + wm) * 4 + kk) * 2 + half) * 32 + n) * 8);
#pragma unroll
        for (int kk = 0; kk < 4; ++kk) {
            bf16x8 bv[2];
#pragma unroll
            for (int ni = 0; ni < 2; ++ni) {
                int hp = hp0[ni] + toff;
                bv[ni] = *(const bf16x8*)(sm + ((hp * 128 + kk * 32 + half * 16) ^ ((hp & 7) << 4)));
            }
#pragma unroll
            for (int ni = 0; ni < 2; ++ni)
                acc[ni] = __builtin_amdgcn_mfma_f32_32x32x16_bf16(
                    a[kk], bv[ni], acc[ni], 0, 0, 0);
        }
    }

    // epilogue: fp32 NCHW + bias (lanes span pixels -> full 64B lines)
#pragma unroll
    for (int ni = 0; ni < 2; ++ni) {
        int gp = (ty0 + pyb + ni * 2) * 128 + tx0 + px;
        float* o = out + (size_t)b * 64 * HW + gp;
        int cob = wm * 32 + half * 4;
#pragma unroll
        for (int g = 0; g < 4; ++g)
#pragma unroll
            for (int r = 0; r < 4; ++r) {
                int co = cob + g * 8 + r;
                o[(size_t)co * HW] = acc[ni][g * 4 + r] + bias[co];
            }
    }
}

extern "C" void kernel_launch(void* const* d_in, const int* in_sizes, int n_in,
                              void* d_out, int out_size, void* d_ws, size_t ws_size,
                              hipStream_t stream) {
    const float* x      = (const float*)d_in[0];
    const float* W_off  = (const float*)d_in[1];
    const float* W_conv = (const float*)d_in[2];
    const float* b_conv = (const float*)d_in[3];

    unsigned short* xh   = (unsigned short*)d_ws;             // 16.8 MB
    unsigned int*   offsu = (unsigned int*)(xh + (size_t)DB * HW * 64);  // 16.8 MB
    unsigned short* wt1  = (unsigned short*)(offsu + (size_t)DB * HW * 64);  // 147 KB
    unsigned short* wt2  = wt1 + 9 * 128 * 64;                // 74 KB
    float* out = (float*)d_out;

    prep_kernel<<<2048 + 432, 256, 0, stream>>>(x, W_off, W_conv, xh, wt1, wt2);

    conv1_kernel<<<dim3(64, DB), 512, 0, stream>>>(xh, wt1, offsu);

    conv2_deform_kernel<<<dim3(64, DB), 512, 0, stream>>>(
        xh, offsu, wt2, b_conv, out);
}